// Round 1
// baseline (1043.698 us; speedup 1.0000x reference)
//
#include <hip/hip_runtime.h>
#include <cstdint>
#include <cstddef>

#define LOG2E 1.4426950408889634f

__device__ __forceinline__ float fexp2(float x) {
#if __has_builtin(__builtin_amdgcn_exp2f)
  return __builtin_amdgcn_exp2f(x);
#else
  return exp2f(x);
#endif
}

__device__ __forceinline__ float frcp(float x) {
#if __has_builtin(__builtin_amdgcn_rcpf)
  return __builtin_amdgcn_rcpf(x);
#else
  return 1.0f / x;
#endif
}

// broadcast lane l's value of v to all lanes via SGPR
__device__ __forceinline__ float rl(float v, int l) {
  return __int_as_float(__builtin_amdgcn_readlane(__float_as_int(v), l));
}

// One wave (64 lanes) per batch element.
// Lane k owns gate row k of W_hh (k: 0-15 = i, 16-31 = f, 32-47 = g, 48-63 = o).
// Weights prescaled by -log2e (or -2log2e for g) so sigmoid/tanh use raw v_exp_f32.
__global__ __launch_bounds__(64) void lstm_gen_kernel(
    const float* __restrict__ x, const float* __restrict__ h0,
    const float* __restrict__ c0, const float* __restrict__ W_ih,
    const float* __restrict__ W_hh, const float* __restrict__ b_ih,
    const float* __restrict__ b_hh, const float* __restrict__ W1,
    const float* __restrict__ b1, const float* __restrict__ W2,
    const float* __restrict__ b2, float* __restrict__ out, int T) {
  const int b = blockIdx.x;
  const int lane = threadIdx.x;      // 0..63
  const int j = lane & 15;           // hidden index within gate block
  const int type = lane >> 4;        // 0 i, 1 f, 2 g, 3 o

  __shared__ float hbuf[4 * 80];     // stride 80 words: <=2-way bank aliasing (free)

  const float sk = (type == 2) ? (-2.0f * LOG2E) : (-LOG2E);
  const float Aact = (type == 2) ? 2.0f : 1.0f;
  const float Bact = (type == 2) ? -1.0f : 0.0f;

  // recurrent weights, prescaled, 16 VGPRs
  float w[16];
#pragma unroll
  for (int jj = 0; jj < 16; ++jj) w[jj] = W_hh[lane * 16 + jj] * sk;
  const float wi = W_ih[lane] * sk;
  const float bk = (b_ih[lane] + b_hh[lane]) * sk;

  // MLP weights: lane holds W1 row (lane&15)
  float w1r[16];
#pragma unroll
  for (int jj = 0; jj < 16; ++jj) w1r[jj] = W1[j * 16 + jj];
  const float b1r = b1[j];
  const float w2r = W2[j];
  const float b2v = b2[0];

  // replicated state: every lane keeps h[j], c[j] for its j = lane&15
  float h = h0[b * 16 + j];
  float c = c0[b * 16 + j];

  const float* xrow = x + (size_t)b * (size_t)T;
  float* orow = out + (size_t)b * (size_t)T;
  const int T4 = T >> 2;
  const float4* xrow4 = (const float4*)xrow;

  // 3-deep register prefetch pipeline for x (distance ~8 steps)
  float4 xa = xrow4[0];
  float4 xb = xrow4[(1 < T4) ? 1 : 0];
  float4 xc2 = xrow4[(2 < T4) ? 2 : 0];

#pragma unroll 1
  for (int t4i = 0; t4i < T4; ++t4i) {
    const float4 xcur = xa;
    xa = xb;
    xb = xc2;
    int nidx = t4i + 3;
    nidx = (nidx < T4) ? nidx : (T4 - 1);
    xc2 = xrow4[nidx];

#pragma unroll
    for (int tt = 0; tt < 4; ++tt) {
      const float xv = (tt == 0) ? xcur.x : (tt == 1) ? xcur.y
                        : (tt == 2) ? xcur.z : xcur.w;
      // gate_k = sk*( W_ih[k]*x + b_ih[k]+b_hh[k] + sum_j W_hh[k][j]*h[j] )
      float a0 = fmaf(wi, xv, bk);
      float a1 = 0.0f, a2 = 0.0f, a3 = 0.0f;
#pragma unroll
      for (int jj = 0; jj < 16; jj += 4) {
        a0 = fmaf(rl(h, jj + 0), w[jj + 0], a0);
        a1 = fmaf(rl(h, jj + 1), w[jj + 1], a1);
        a2 = fmaf(rl(h, jj + 2), w[jj + 2], a2);
        a3 = fmaf(rl(h, jj + 3), w[jj + 3], a3);
      }
      const float gacc = (a0 + a1) + (a2 + a3);
      // i,f,o: sigmoid = rcp(1+2^gacc); g: tanh = 2*rcp(1+2^gacc)-1
      const float act = fmaf(Aact, frcp(1.0f + fexp2(gacc)), Bact);

      const float iv = __shfl(act, j);
      const float fv = __shfl(act, j + 16);
      const float gv = __shfl(act, j + 32);
      const float ov = __shfl(act, j + 48);

      c = fmaf(fv, c, iv * gv);
      // tanh(c) = 1 - 2*rcp(1 + 2^(2*log2e*c))
      const float tc = fmaf(-2.0f, frcp(1.0f + fexp2(c * (2.0f * LOG2E))), 1.0f);
      h = ov * tc;
      hbuf[tt * 80 + lane] = h;   // stash for batched MLP head
    }

    // MLP head, batched over the 4 timesteps: group q (lanes 16q..16q+15)
    // handles timestep t4i*4 + q; lane computes y2[j] of that step.
    const int q = type;
    const float4 hA = *(const float4*)&hbuf[q * 80 + 0];
    const float4 hB = *(const float4*)&hbuf[q * 80 + 4];
    const float4 hC = *(const float4*)&hbuf[q * 80 + 8];
    const float4 hD = *(const float4*)&hbuf[q * 80 + 12];

    float m0 = fmaf(fmaxf(hA.x, 0.0f), w1r[0], b1r);
    float m1 = fmaxf(hA.y, 0.0f) * w1r[1];
    float m2 = fmaxf(hA.z, 0.0f) * w1r[2];
    float m3 = fmaxf(hA.w, 0.0f) * w1r[3];
    m0 = fmaf(fmaxf(hB.x, 0.0f), w1r[4], m0);
    m1 = fmaf(fmaxf(hB.y, 0.0f), w1r[5], m1);
    m2 = fmaf(fmaxf(hB.z, 0.0f), w1r[6], m2);
    m3 = fmaf(fmaxf(hB.w, 0.0f), w1r[7], m3);
    m0 = fmaf(fmaxf(hC.x, 0.0f), w1r[8], m0);
    m1 = fmaf(fmaxf(hC.y, 0.0f), w1r[9], m1);
    m2 = fmaf(fmaxf(hC.z, 0.0f), w1r[10], m2);
    m3 = fmaf(fmaxf(hC.w, 0.0f), w1r[11], m3);
    m0 = fmaf(fmaxf(hD.x, 0.0f), w1r[12], m0);
    m1 = fmaf(fmaxf(hD.y, 0.0f), w1r[13], m1);
    m2 = fmaf(fmaxf(hD.z, 0.0f), w1r[14], m2);
    m3 = fmaf(fmaxf(hD.w, 0.0f), w1r[15], m3);
    const float y2 = (m0 + m1) + (m2 + m3);
    const float y2r = fmaxf(y2, 0.0f);

    // reduce y2r * W2 over the 16 lanes of the group
    float v = y2r * w2r;
    v += __shfl_xor(v, 1);
    v += __shfl_xor(v, 2);
    v += __shfl_xor(v, 4);
    v += __shfl_xor(v, 8);
    const float z = v + b2v;
    // tanh(z) = 1 - 2*rcp(1 + 2^(2*log2e*z))
    const float y3 = 1.0f - 2.0f * frcp(1.0f + fexp2(z * (2.0f * LOG2E)));

    if (j == 0) orow[t4i * 4 + q] = y3;
  }
}

extern "C" void kernel_launch(void* const* d_in, const int* in_sizes, int n_in,
                              void* d_out, int out_size, void* d_ws,
                              size_t ws_size, hipStream_t stream) {
  (void)n_in; (void)d_ws; (void)ws_size;
  const float* x = (const float*)d_in[0];
  const float* h0 = (const float*)d_in[1];
  const float* c0 = (const float*)d_in[2];
  const float* W_ih = (const float*)d_in[3];
  const float* W_hh = (const float*)d_in[4];
  const float* b_ih = (const float*)d_in[5];
  const float* b_hh = (const float*)d_in[6];
  const float* W1 = (const float*)d_in[7];
  const float* b1 = (const float*)d_in[8];
  const float* W2 = (const float*)d_in[9];
  const float* b2 = (const float*)d_in[10];

  const int B = in_sizes[1] / 16;           // h0 is [B,16]
  const int T = in_sizes[0] / (B > 0 ? B : 1);

  lstm_gen_kernel<<<B, 64, 0, stream>>>(x, h0, c0, W_ih, W_hh, b_ih, b_hh,
                                        W1, b1, W2, b2, (float*)d_out, T);
}